// Round 1
// baseline (800.039 us; speedup 1.0000x reference)
//
#include <hip/hip_runtime.h>
#include <math.h>
#include <stdint.h>

#define N_TOK   8192      // B*S = 4*2048
#define DMODEL  1024
#define DCODEX  64
#define KCODES  8192

// ---------------------------------------------------------------------------
// cn2[k] = sum_d codex[k][d]^2
__global__ __launch_bounds__(256) void codenorm_kernel(const float* __restrict__ codex,
                                                       float* __restrict__ cn2) {
    int k = blockIdx.x * 256 + threadIdx.x;
    const float4* p = (const float4*)(codex + (size_t)k * DCODEX);
    float s = 0.f;
#pragma unroll
    for (int i = 0; i < 16; ++i) {
        float4 v = p[i];
        s += v.x * v.x + v.y * v.y + v.z * v.z + v.w * v.w;
    }
    cn2[k] = s;
}

// ---------------------------------------------------------------------------
// H = tanh(Z @ W1 + b1), (8192 x 1024) = (8192 x 1024)(1024 x 1024)
// block tile 128 x 256, 256 threads, thread tile 16 x 8
__global__ __launch_bounds__(256, 2) void gemm1_tanh_kernel(const float* __restrict__ Z,
                                                            const float* __restrict__ W1,
                                                            const float* __restrict__ b1,
                                                            float* __restrict__ H) {
    __shared__ float As[16][132];   // As[k][m]  (A transposed)
    __shared__ float Bs[16][260];   // Bs[k][n]
    const int tid = threadIdx.x;
    const int row0 = blockIdx.x * 128;
    const int col0 = blockIdx.y * 256;
    const int ty = tid >> 5;    // 8 groups x 16 rows
    const int tx = tid & 31;    // 32 groups x 8 cols

    float acc[16][8];
#pragma unroll
    for (int i = 0; i < 16; ++i)
#pragma unroll
        for (int j = 0; j < 8; ++j) acc[i][j] = 0.f;

    for (int k0 = 0; k0 < DMODEL; k0 += 16) {
        // A tile: 128 rows x 16 k  (512 float4, 2 per thread), store transposed
#pragma unroll
        for (int t = 0; t < 2; ++t) {
            int q = tid + t * 256;
            int r = q >> 2;
            int kc = (q & 3) * 4;
            float4 v = *(const float4*)(Z + (size_t)(row0 + r) * DMODEL + k0 + kc);
            As[kc + 0][r] = v.x; As[kc + 1][r] = v.y;
            As[kc + 2][r] = v.z; As[kc + 3][r] = v.w;
        }
        // B tile: 16 k x 256 cols (1024 float4, 4 per thread)
#pragma unroll
        for (int t = 0; t < 4; ++t) {
            int q = tid + t * 256;
            int kk = q >> 6;
            int c4 = (q & 63) * 4;
            *(float4*)&Bs[kk][c4] =
                *(const float4*)(W1 + (size_t)(k0 + kk) * DMODEL + col0 + c4);
        }
        __syncthreads();
#pragma unroll
        for (int k = 0; k < 16; ++k) {
            float a[16], b[8];
            *(float4*)&a[0]  = *(const float4*)&As[k][ty * 16 + 0];
            *(float4*)&a[4]  = *(const float4*)&As[k][ty * 16 + 4];
            *(float4*)&a[8]  = *(const float4*)&As[k][ty * 16 + 8];
            *(float4*)&a[12] = *(const float4*)&As[k][ty * 16 + 12];
            *(float4*)&b[0]  = *(const float4*)&Bs[k][tx * 8 + 0];
            *(float4*)&b[4]  = *(const float4*)&Bs[k][tx * 8 + 4];
#pragma unroll
            for (int i = 0; i < 16; ++i)
#pragma unroll
                for (int j = 0; j < 8; ++j)
                    acc[i][j] = fmaf(a[i], b[j], acc[i][j]);
        }
        __syncthreads();
    }
    float bv[8];
    *(float4*)&bv[0] = *(const float4*)(b1 + col0 + tx * 8);
    *(float4*)&bv[4] = *(const float4*)(b1 + col0 + tx * 8 + 4);
#pragma unroll
    for (int i = 0; i < 16; ++i) {
        float o[8];
#pragma unroll
        for (int j = 0; j < 8; ++j) o[j] = tanhf(acc[i][j] + bv[j]);
        size_t off = (size_t)(row0 + ty * 16 + i) * DMODEL + col0 + tx * 8;
        *(float4*)(H + off)     = *(float4*)&o[0];
        *(float4*)(H + off + 4) = *(float4*)&o[4];
    }
}

// ---------------------------------------------------------------------------
// E = H @ W2 + b2 ; Ze = E / max(||E||_row, 1e-12)
// block tile 64 tokens x 64 cols, 256 threads (16x16), thread 4x4
__global__ __launch_bounds__(256) void gemm2_norm_kernel(const float* __restrict__ H,
                                                         const float* __restrict__ W2,
                                                         const float* __restrict__ b2,
                                                         float* __restrict__ Ze) {
    __shared__ float As[32][68];   // As[k][m] transposed
    __shared__ float Bs[32][68];   // Bs[k][n]
    const int tid = threadIdx.x;
    const int row0 = blockIdx.x * 64;
    const int ty = tid >> 4, tx = tid & 15;

    float acc[4][4];
#pragma unroll
    for (int i = 0; i < 4; ++i)
#pragma unroll
        for (int j = 0; j < 4; ++j) acc[i][j] = 0.f;

    for (int k0 = 0; k0 < DMODEL; k0 += 32) {
#pragma unroll
        for (int t = 0; t < 2; ++t) {
            int q = tid + t * 256;
            int r = q >> 3;
            int k4 = (q & 7) * 4;
            float4 v = *(const float4*)(H + (size_t)(row0 + r) * DMODEL + k0 + k4);
            As[k4 + 0][r] = v.x; As[k4 + 1][r] = v.y;
            As[k4 + 2][r] = v.z; As[k4 + 3][r] = v.w;
        }
#pragma unroll
        for (int t = 0; t < 2; ++t) {
            int q = tid + t * 256;
            int kk = q >> 4;
            int c4 = (q & 15) * 4;
            *(float4*)&Bs[kk][c4] = *(const float4*)(W2 + (size_t)(k0 + kk) * DCODEX + c4);
        }
        __syncthreads();
#pragma unroll
        for (int k = 0; k < 32; ++k) {
            float4 a = *(const float4*)&As[k][ty * 4];
            float4 b = *(const float4*)&Bs[k][tx * 4];
            float av[4] = {a.x, a.y, a.z, a.w};
            float bw[4] = {b.x, b.y, b.z, b.w};
#pragma unroll
            for (int i = 0; i < 4; ++i)
#pragma unroll
                for (int j = 0; j < 4; ++j)
                    acc[i][j] = fmaf(av[i], bw[j], acc[i][j]);
        }
        __syncthreads();
    }
    float4 b2v4 = *(const float4*)(b2 + tx * 4);
    float b2v[4] = {b2v4.x, b2v4.y, b2v4.z, b2v4.w};
#pragma unroll
    for (int i = 0; i < 4; ++i) {
        float e[4];
#pragma unroll
        for (int j = 0; j < 4; ++j) e[j] = acc[i][j] + b2v[j];
        float ss = e[0] * e[0] + e[1] * e[1] + e[2] * e[2] + e[3] * e[3];
        ss += __shfl_xor(ss, 8, 64);
        ss += __shfl_xor(ss, 4, 64);
        ss += __shfl_xor(ss, 2, 64);
        ss += __shfl_xor(ss, 1, 64);
        float nrm = fmaxf(sqrtf(ss), 1e-12f);
        float o[4];
#pragma unroll
        for (int j = 0; j < 4; ++j) o[j] = e[j] / nrm;
        *(float4*)(Ze + (size_t)(row0 + ty * 4 + i) * DCODEX + tx * 4) = *(float4*)&o[0];
    }
}

// ---------------------------------------------------------------------------
// argmin_k (cn2[k] - 2 * z.c_k) per token; packed u64 atomicMin (val-enc | idx)
// grid (64 token tiles, 8 code strips of 1024); block tile 128 tok x 128 codes
__device__ __forceinline__ unsigned fenc(float f) {
    unsigned u = __float_as_uint(f);
    return (u & 0x80000000u) ? ~u : (u | 0x80000000u);
}

__global__ __launch_bounds__(256) void dist_argmin_kernel(const float* __restrict__ Ze,
                                                          const float* __restrict__ codex,
                                                          const float* __restrict__ cn2,
                                                          unsigned long long* __restrict__ gbest) {
    __shared__ float Zs[64][132];   // Zs[d][token]
    __shared__ float Cs[32][132];   // Cs[d][code], half of K at a time
    __shared__ unsigned long long red[128];
    const int tid = threadIdx.x;
    const int row0 = blockIdx.x * 128;
    const int strip0 = blockIdx.y * 1024;
    const int ty = tid >> 4, tx = tid & 15;

    if (tid < 128) red[tid] = 0xFFFFFFFFFFFFFFFFull;
    // stage Z tile (128 tokens x 64 d), transposed
#pragma unroll
    for (int t = 0; t < 8; ++t) {
        int q = tid + t * 256;
        int r = q >> 4;
        int d4 = (q & 15) * 4;
        float4 v = *(const float4*)(Ze + (size_t)(row0 + r) * DCODEX + d4);
        Zs[d4 + 0][r] = v.x; Zs[d4 + 1][r] = v.y;
        Zs[d4 + 2][r] = v.z; Zs[d4 + 3][r] = v.w;
    }

    float bv[8];
    int bi[8];
#pragma unroll
    for (int i = 0; i < 8; ++i) { bv[i] = INFINITY; bi[i] = 0; }

    for (int c0 = 0; c0 < 1024; c0 += 128) {
        const int cbase = strip0 + c0;
        float cn[8];
        *(float4*)&cn[0] = *(const float4*)(cn2 + cbase + tx * 8);
        *(float4*)&cn[4] = *(const float4*)(cn2 + cbase + tx * 8 + 4);
        float s[8][8];
#pragma unroll
        for (int i = 0; i < 8; ++i)
#pragma unroll
            for (int j = 0; j < 8; ++j) s[i][j] = 0.f;

        for (int h = 0; h < 2; ++h) {
            __syncthreads();   // WAR on Cs (also orders Zs stores before first use)
#pragma unroll
            for (int t = 0; t < 4; ++t) {
                int q = tid + t * 256;
                int c = q >> 3;
                int d4 = (q & 7) * 4;
                float4 v = *(const float4*)(codex + (size_t)(cbase + c) * DCODEX + h * 32 + d4);
                Cs[d4 + 0][c] = v.x; Cs[d4 + 1][c] = v.y;
                Cs[d4 + 2][c] = v.z; Cs[d4 + 3][c] = v.w;
            }
            __syncthreads();
#pragma unroll
            for (int d = 0; d < 32; ++d) {
                float a[8], b[8];
                *(float4*)&a[0] = *(const float4*)&Zs[h * 32 + d][ty * 8];
                *(float4*)&a[4] = *(const float4*)&Zs[h * 32 + d][ty * 8 + 4];
                *(float4*)&b[0] = *(const float4*)&Cs[d][tx * 8];
                *(float4*)&b[4] = *(const float4*)&Cs[d][tx * 8 + 4];
#pragma unroll
                for (int i = 0; i < 8; ++i)
#pragma unroll
                    for (int j = 0; j < 8; ++j)
                        s[i][j] = fmaf(a[i], b[j], s[i][j]);
            }
        }
#pragma unroll
        for (int i = 0; i < 8; ++i)
#pragma unroll
            for (int j = 0; j < 8; ++j) {
                float dist = fmaf(-2.0f, s[i][j], cn[j]);
                if (dist < bv[i]) { bv[i] = dist; bi[i] = cbase + tx * 8 + j; }
            }
    }
#pragma unroll
    for (int i = 0; i < 8; ++i) {
        unsigned long long key =
            ((unsigned long long)fenc(bv[i]) << 32) | (unsigned)bi[i];
        atomicMin(&red[ty * 8 + i], key);
    }
    __syncthreads();
    if (tid < 128) atomicMin(&gbest[row0 + tid], red[tid]);
}

// ---------------------------------------------------------------------------
__global__ __launch_bounds__(256) void scatter_onehot_kernel(const unsigned long long* __restrict__ gbest,
                                                             int* __restrict__ idxbuf,
                                                             float* __restrict__ probs) {
    int n = blockIdx.x * 256 + threadIdx.x;
    unsigned id = (unsigned)(gbest[n] & 0xFFFFFFFFull);
    idxbuf[n] = (int)id;
    probs[(size_t)n * KCODES + id] = 1.0f;
}

// ---------------------------------------------------------------------------
// gather codex[idx], STE val = ze + (zq - ze), LayerNorm(64), @ Wp + bp; loss
// block: 16 tokens, 256 threads (4 waves, 1 wave = 1 row slice of 64 lanes)
__global__ __launch_bounds__(256) void ln_gemm3_loss_kernel(const int* __restrict__ idxbuf,
                                                            const float* __restrict__ codex,
                                                            const float* __restrict__ Ze,
                                                            const float* __restrict__ ln_w,
                                                            const float* __restrict__ ln_b,
                                                            const float* __restrict__ Wp,
                                                            const float* __restrict__ bp,
                                                            float* __restrict__ Zq,
                                                            float* __restrict__ loss) {
    __shared__ float A[16][64];
    __shared__ float lossAcc;
    const int tid = threadIdx.x;
    const int row0 = blockIdx.x * 16;
    if (tid == 0) lossAcc = 0.f;
    __syncthreads();
    const int w = tid >> 6, l = tid & 63;
    const float lw = ln_w[l], lb = ln_b[l];
    float lsum = 0.f;
#pragma unroll
    for (int g = 0; g < 4; ++g) {
        int r = w * 4 + g;
        int row = row0 + r;
        int id = idxbuf[row];
        float zq = codex[(size_t)id * DCODEX + l];
        float ze = Ze[(size_t)row * DCODEX + l];
        float dlt = zq - ze;
        float val = ze + dlt;   // STE forward value, matching reference rounding
        float s = val;
#pragma unroll
        for (int m = 32; m >= 1; m >>= 1) s += __shfl_xor(s, m, 64);
        float mu = s * 0.015625f;
        float c = val - mu;
        float v2 = c * c;
#pragma unroll
        for (int m = 32; m >= 1; m >>= 1) v2 += __shfl_xor(v2, m, 64);
        float var = v2 * 0.015625f;
        float y = c * (1.0f / sqrtf(var + 1e-5f)) * lw + lb;
        A[r][l] = y;
        float d2 = dlt * dlt;
#pragma unroll
        for (int m = 32; m >= 1; m >>= 1) d2 += __shfl_xor(d2, m, 64);
        if (l == 0) lsum += d2;
    }
    if (l == 0) atomicAdd(&lossAcc, lsum);
    __syncthreads();
    if (tid == 0) atomicAdd(loss, lossAcc * (1.0f / 524288.0f));  // BETA=1, /(N*64)

    // GEMM: out[n][j] = sum_d A[n][d] * Wp[d][j] + bp[j]
#pragma unroll 1
    for (int jj = 0; jj < 4; ++jj) {
        int j = jj * 256 + tid;
        float wp[64];
#pragma unroll
        for (int d = 0; d < 64; ++d) wp[d] = Wp[(size_t)d * DMODEL + j];
        float bias = bp[j];
#pragma unroll 1
        for (int n = 0; n < 16; ++n) {
            float acc = bias;
#pragma unroll
            for (int d4 = 0; d4 < 16; ++d4) {
                float4 av = *(const float4*)&A[n][d4 * 4];
                acc = fmaf(av.x, wp[d4 * 4 + 0], acc);
                acc = fmaf(av.y, wp[d4 * 4 + 1], acc);
                acc = fmaf(av.z, wp[d4 * 4 + 2], acc);
                acc = fmaf(av.w, wp[d4 * 4 + 3], acc);
            }
            Zq[(size_t)(row0 + n) * DMODEL + j] = acc;
        }
    }
}

// ---------------------------------------------------------------------------
extern "C" void kernel_launch(void* const* d_in, const int* in_sizes, int n_in,
                              void* d_out, int out_size, void* d_ws, size_t ws_size,
                              hipStream_t stream) {
    const float* Z     = (const float*)d_in[0];
    const float* W1    = (const float*)d_in[1];
    const float* b1    = (const float*)d_in[2];
    const float* W2    = (const float*)d_in[3];
    const float* b2    = (const float*)d_in[4];
    const float* codex = (const float*)d_in[5];
    const float* ln_w  = (const float*)d_in[6];
    const float* ln_b  = (const float*)d_in[7];
    const float* Wp    = (const float*)d_in[8];
    const float* bp    = (const float*)d_in[9];

    float* out      = (float*)d_out;
    float* Zq_out   = out;                       // 8192*1024
    float* loss_out = out + (size_t)N_TOK * DMODEL;        // 1
    float* probs    = loss_out + 1;              // 8192*8192

    // workspace layout (~34.1 MB)
    char* ws = (char*)d_ws;
    float* H   = (float*)ws;                                   // 8192*1024
    float* Ze  = H + (size_t)N_TOK * DMODEL;                   // 8192*64
    float* cn2 = Ze + (size_t)N_TOK * DCODEX;                  // 8192
    unsigned long long* gbest = (unsigned long long*)(cn2 + KCODES);  // 8192 (8B-aligned)
    int* idxbuf = (int*)(gbest + N_TOK);                       // 8192

    // zero loss + probs region; init gbest to +inf keys
    hipMemsetAsync(loss_out, 0, (size_t)(1 + (size_t)N_TOK * KCODES) * sizeof(float), stream);
    hipMemsetAsync(gbest, 0xFF, (size_t)N_TOK * sizeof(unsigned long long), stream);

    codenorm_kernel<<<KCODES / 256, 256, 0, stream>>>(codex, cn2);
    gemm1_tanh_kernel<<<dim3(N_TOK / 128, DMODEL / 256), 256, 0, stream>>>(Z, W1, b1, H);
    gemm2_norm_kernel<<<N_TOK / 64, 256, 0, stream>>>(H, W2, b2, Ze);
    dist_argmin_kernel<<<dim3(N_TOK / 128, KCODES / 1024), 256, 0, stream>>>(Ze, codex, cn2, gbest);
    scatter_onehot_kernel<<<N_TOK / 256, 256, 0, stream>>>(gbest, idxbuf, probs);
    ln_gemm3_loss_kernel<<<N_TOK / 16, 256, 0, stream>>>(idxbuf, codex, Ze, ln_w, ln_b,
                                                         Wp, bp, Zq_out, loss_out);
}